// Round 3
// baseline (67.644 us; speedup 1.0000x reference)
//
#include <hip/hip_runtime.h>

// Cost volume: corr[b, dyi*9+dxi, y, x] = sum_c f1[b,c,y,x] * f2[b,c,y+dyi-4,x+dxi-4]
// (OOB f2 = 0). B=4, C=256, H=W=96, patch 9x9.
//
// Round 3:
//  - Keep round-2 structure (256-thr blocks, 4-way channel split + LDS tree
//    reduction, bijective XCD swizzle, whole grid co-resident).
//  - Halve L1 traffic: load only f1 + f2-M per channel; L/R windows come from
//    neighbor lanes via __shfl_up/down (lane i's L == lane i-1's M, same row).
//    Row-edge lanes need zeros anyway (hasL/hasR), so the only real fixup is
//    wave-boundary lanes 0/63 mid-row, which do a 1-lane exec-masked load.

#define NB 4
#define NC 256
#define NH 96
#define NW 96
#define MAXD 4
#define NP 9
#define XCH (NW / 4)            // 24 x-chunks per row
#define NCHUNK (NB * NH * XCH)  // 9216 chunks
#define PLANE (NH * NW)         // 9216 floats per (b,c) plane
#define NGRP (NCHUNK / 64)      // 144 chunk-groups
#define NBLK (NP * NGRP)        // 1296 blocks
#define CPW (NC / 4)            // 64 channels per wave
#define LPAD 37                 // 36 acc floats padded to 37 (coprime with 32 banks)

__global__ __launch_bounds__(256) void costvol_kernel(
    const float* __restrict__ f1, const float* __restrict__ f2,
    float* __restrict__ out)
{
    __shared__ float lds[2 * 64 * LPAD];  // 18,944 B

    const int bid = blockIdx.x;
    const int swz = (bid & 7) * (NBLK / 8) + (bid >> 3);
    const int dyi = swz % NP;
    const int g   = swz / NP;

    const int w    = threadIdx.x >> 6;   // wave 0..3
    const int lane = threadIdx.x & 63;

    const int chk = g * 64 + lane;       // 0..9215
    const int b   = chk / (NH * XCH);
    const int rem = chk - b * (NH * XCH);
    const int y   = rem / XCH;
    const int x0  = (rem - y * XCH) * 4;
    const int y2  = y + dyi - MAXD;

    float acc[NP][4];
#pragma unroll
    for (int i = 0; i < NP; ++i)
#pragma unroll
        for (int j = 0; j < 4; ++j) acc[i][j] = 0.f;

    if (y2 >= 0 && y2 < NH) {
        const float* p1 = f1 + ((b * NC + w * CPW) * NH + y)  * NW + x0;
        const float* p2 = f2 + ((b * NC + w * CPW) * NH + y2) * NW + x0;
        const bool hasL = (x0 >= 4);        // left window in-bounds
        const bool hasR = (x0 <= NW - 8);   // right window in-bounds
        const bool edgeLo = (lane == 0)  && hasL;  // neighbor not in wave
        const bool edgeHi = (lane == 63) && hasR;
#pragma unroll 4
        for (int c = 0; c < CPW; ++c) {
            const float4 av = *(const float4*)p1;
            const float4 Mv = *(const float4*)p2;
            float4 Lv, Rv;
            Lv.x = __shfl_up(Mv.x, 1);
            Lv.y = __shfl_up(Mv.y, 1);
            Lv.z = __shfl_up(Mv.z, 1);
            Lv.w = __shfl_up(Mv.w, 1);
            Rv.x = __shfl_down(Mv.x, 1);
            Rv.y = __shfl_down(Mv.y, 1);
            Rv.z = __shfl_down(Mv.z, 1);
            Rv.w = __shfl_down(Mv.w, 1);
            if (edgeLo) Lv = *(const float4*)(p2 - 4);   // 1-lane masked load
            if (edgeHi) Rv = *(const float4*)(p2 + 4);   // 1-lane masked load
            if (!hasL)  Lv = make_float4(0.f, 0.f, 0.f, 0.f);
            if (!hasR)  Rv = make_float4(0.f, 0.f, 0.f, 0.f);

            const float wv[12] = {Lv.x, Lv.y, Lv.z, Lv.w,
                                  Mv.x, Mv.y, Mv.z, Mv.w,
                                  Rv.x, Rv.y, Rv.z, Rv.w};
            const float a[4] = {av.x, av.y, av.z, av.w};
#pragma unroll
            for (int dxi = 0; dxi < NP; ++dxi)
#pragma unroll
                for (int j = 0; j < 4; ++j)
                    acc[dxi][j] += a[j] * wv[dxi + j];
            p1 += PLANE;
            p2 += PLANE;
        }
    }

    // ---- two-stage cross-wave reduction
    float* reg0 = &lds[0 * 64 * LPAD + lane * LPAD];
    float* reg1 = &lds[1 * 64 * LPAD + lane * LPAD];

    if (w >= 2) {
        float* dst = (w == 2) ? reg0 : reg1;
#pragma unroll
        for (int dxi = 0; dxi < NP; ++dxi)
#pragma unroll
            for (int j = 0; j < 4; ++j) dst[dxi * 4 + j] = acc[dxi][j];
    }
    __syncthreads();
    if (w < 2) {
        const float* src = (w == 0) ? reg0 : reg1;
#pragma unroll
        for (int dxi = 0; dxi < NP; ++dxi)
#pragma unroll
            for (int j = 0; j < 4; ++j) acc[dxi][j] += src[dxi * 4 + j];
    }
    __syncthreads();
    if (w == 1) {
#pragma unroll
        for (int dxi = 0; dxi < NP; ++dxi)
#pragma unroll
            for (int j = 0; j < 4; ++j) reg0[dxi * 4 + j] = acc[dxi][j];
    }
    __syncthreads();
    if (w == 0) {
#pragma unroll
        for (int dxi = 0; dxi < NP; ++dxi)
#pragma unroll
            for (int j = 0; j < 4; ++j) acc[dxi][j] += reg0[dxi * 4 + j];

        float* ob = out + ((b * (NP * NP) + dyi * NP) * NH + y) * NW + x0;
#pragma unroll
        for (int dxi = 0; dxi < NP; ++dxi) {
            *(float4*)ob = make_float4(acc[dxi][0], acc[dxi][1], acc[dxi][2], acc[dxi][3]);
            ob += PLANE;
        }
    }
}

extern "C" void kernel_launch(void* const* d_in, const int* in_sizes, int n_in,
                              void* d_out, int out_size, void* d_ws, size_t ws_size,
                              hipStream_t stream) {
    const float* f1 = (const float*)d_in[0];
    const float* f2 = (const float*)d_in[1];
    float* out = (float*)d_out;
    costvol_kernel<<<dim3(NBLK, 1, 1), dim3(256, 1, 1), 0, stream>>>(f1, f2, out);
}

// Round 4
// 49.330 us; speedup vs baseline: 1.3713x; 1.3713x over previous
//
#include <hip/hip_runtime.h>

// Cost volume: corr[b, dyi*9+dxi, y, x] = sum_c f1[b,c,y,x] * f2[b,c,y+dyi-4,x+dxi-4]
// (OOB f2 = 0). B=4, C=256, H=W=96, patch 9x9.
//
// Round 4 (revert round-3 shuffles; widen + pack):
//  - x-width 8 per thread: window [x0-4, x0+11] = 6 float4 loads per channel
//    serving 72 FMAs (bytes/FMA 1.78 -> 1.33; L1 floor ~26us).
//  - Packed f32: v2f (ext_vector_type(2)) acc/operands -> v_pk_fma_f32.
//    acc2[dxi][j] += a2[j] * (w[dxi+2j], w[dxi+2j+1]); even dxi uses natural
//    pairs W[m]=(w[2m],w[2m+1]), odd dxi uses shifted pairs O[m]=(w[2m+1],w[2m+2]).
//  - 4-way channel split, 256-thr blocks, 648 blocks (=8*81, bijective XCD
//    swizzle, dy fastest per XCD), 2-phase 4-region LDS tree reduction.

#define NB 4
#define NC 256
#define NH 96
#define NW 96
#define MAXD 4
#define NP 9
#define XC8 (NW / 8)             // 12 x8-chunks per row
#define NCH8 (NB * NH * XC8)     // 4608 chunks
#define PLANE (NH * NW)          // 9216 floats per (b,c) plane
#define NGRP (NCH8 / 64)         // 72 chunk-groups
#define NBLK (NP * NGRP)         // 648 blocks
#define CPW (NC / 4)             // 64 channels per wave
#define RSTRIDE 36               // floats per lane region (144B, 16B-aligned)

typedef float v2f __attribute__((ext_vector_type(2)));

__global__ __launch_bounds__(256, 2) void costvol_kernel(
    const float* __restrict__ f1, const float* __restrict__ f2,
    float* __restrict__ out)
{
    __shared__ float lds[4 * 64 * RSTRIDE];  // 36,864 B

    const int bid = blockIdx.x;
    const int swz = (bid & 7) * (NBLK / 8) + (bid >> 3);
    const int dyi = swz % NP;
    const int g   = swz / NP;

    const int w    = threadIdx.x >> 6;   // wave 0..3
    const int lane = threadIdx.x & 63;

    const int chk = g * 64 + lane;       // 0..4607
    const int b   = chk / (NH * XC8);
    const int rem = chk - b * (NH * XC8);
    const int y   = rem / XC8;
    const int xc  = rem - y * XC8;
    const int x0  = xc * 8;
    const int y2  = y + dyi - MAXD;

    v2f acc[NP][4];                      // acc[dxi][j] = outputs x0+2j, x0+2j+1
#pragma unroll
    for (int i = 0; i < NP; ++i)
#pragma unroll
        for (int j = 0; j < 4; ++j) acc[i][j] = (v2f)(0.f);

    if (y2 >= 0 && y2 < NH) {
        const float* p1 = f1 + ((b * NC + w * CPW) * NH + y)  * NW + x0;
        const float* p2 = f2 + ((b * NC + w * CPW) * NH + y2) * NW + x0;
        const bool hasL = (xc > 0);
        const bool hasR = (xc < XC8 - 1);
#pragma unroll 2
        for (int c = 0; c < CPW; ++c) {
            const float4 A0 = *(const float4*)(p1);
            const float4 A1 = *(const float4*)(p1 + 4);
            const float4 F0 = hasL ? *(const float4*)(p2 - 4) : make_float4(0.f, 0.f, 0.f, 0.f);
            const float4 F1 = *(const float4*)(p2);
            const float4 F2 = *(const float4*)(p2 + 4);
            const float4 F3 = hasR ? *(const float4*)(p2 + 8) : make_float4(0.f, 0.f, 0.f, 0.f);

            v2f W[8];                    // natural (even-start) pairs of window
            W[0] = (v2f){F0.x, F0.y}; W[1] = (v2f){F0.z, F0.w};
            W[2] = (v2f){F1.x, F1.y}; W[3] = (v2f){F1.z, F1.w};
            W[4] = (v2f){F2.x, F2.y}; W[5] = (v2f){F2.z, F2.w};
            W[6] = (v2f){F3.x, F3.y}; W[7] = (v2f){F3.z, F3.w};
            v2f O[7];                    // odd-start pairs
#pragma unroll
            for (int m = 0; m < 7; ++m) O[m] = (v2f){W[m].y, W[m + 1].x};
            v2f a2[4];
            a2[0] = (v2f){A0.x, A0.y}; a2[1] = (v2f){A0.z, A0.w};
            a2[2] = (v2f){A1.x, A1.y}; a2[3] = (v2f){A1.z, A1.w};

#pragma unroll
            for (int dxi = 0; dxi < NP; ++dxi) {
#pragma unroll
                for (int j = 0; j < 4; ++j) {
                    const v2f wp = (dxi & 1) ? O[((dxi - 1) >> 1) + j]
                                             : W[(dxi >> 1) + j];
                    acc[dxi][j] += a2[j] * wp;   // -> v_pk_fma_f32
                }
            }
            p1 += PLANE;
            p2 += PLANE;
        }
    }

    // ---- 2-phase (lo = j 0..1, hi = j 2..3) 4-wave tree reduction
    float* const r0 = &lds[(0 * 64 + lane) * RSTRIDE];
    float* const r1 = &lds[(1 * 64 + lane) * RSTRIDE];
    float* const r2 = &lds[(2 * 64 + lane) * RSTRIDE];
    float* const r3 = &lds[(3 * 64 + lane) * RSTRIDE];

#define WRITE_HALF(dst, h)                                         \
    {                                                              \
        _Pragma("unroll") for (int dxi = 0; dxi < NP; ++dxi) {     \
            *(v2f*)((dst) + dxi * 4)     = acc[dxi][2 * (h)];      \
            *(v2f*)((dst) + dxi * 4 + 2) = acc[dxi][2 * (h) + 1];  \
        }                                                          \
    }
#define ADD_HALF(src, h)                                           \
    {                                                              \
        _Pragma("unroll") for (int dxi = 0; dxi < NP; ++dxi) {     \
            acc[dxi][2 * (h)]     += *(const v2f*)((src) + dxi * 4);     \
            acc[dxi][2 * (h) + 1] += *(const v2f*)((src) + dxi * 4 + 2); \
        }                                                          \
    }

    if (w == 2) WRITE_HALF(r0, 0);
    if (w == 3) WRITE_HALF(r1, 0);
    __syncthreads();
    if (w == 0) ADD_HALF(r0, 0);       // w0 lo = w0+w2
    if (w == 1) ADD_HALF(r1, 0);       // w1 lo = w1+w3
    if (w == 2) WRITE_HALF(r2, 1);     // w2 hi
    if (w == 3) WRITE_HALF(r3, 1);     // w3 hi
    __syncthreads();
    if (w == 1) WRITE_HALF(r0, 0);     // lo partial (w1+w3)
    if (w == 0) WRITE_HALF(r1, 1);     // w0 hi
    __syncthreads();

    if (w == 0) {                      // lo final: += (w1+w3)
        ADD_HALF(r0, 0);
        float* ob = out + ((b * (NP * NP) + dyi * NP) * NH + y) * NW + x0;
#pragma unroll
        for (int dxi = 0; dxi < NP; ++dxi) {
            *(float4*)ob = make_float4(acc[dxi][0].x, acc[dxi][0].y,
                                       acc[dxi][1].x, acc[dxi][1].y);
            ob += PLANE;
        }
    }
    if (w == 1) {                      // hi final: own + w2 + w3 + w0
        ADD_HALF(r2, 1);
        ADD_HALF(r3, 1);
        ADD_HALF(r1, 1);
        float* ob = out + ((b * (NP * NP) + dyi * NP) * NH + y) * NW + x0 + 4;
#pragma unroll
        for (int dxi = 0; dxi < NP; ++dxi) {
            *(float4*)ob = make_float4(acc[dxi][2].x, acc[dxi][2].y,
                                       acc[dxi][3].x, acc[dxi][3].y);
            ob += PLANE;
        }
    }
}

extern "C" void kernel_launch(void* const* d_in, const int* in_sizes, int n_in,
                              void* d_out, int out_size, void* d_ws, size_t ws_size,
                              hipStream_t stream) {
    const float* f1 = (const float*)d_in[0];
    const float* f2 = (const float*)d_in[1];
    float* out = (float*)d_out;
    costvol_kernel<<<dim3(NBLK, 1, 1), dim3(256, 1, 1), 0, stream>>>(f1, f2, out);
}